// Round 21
// baseline (293.298 us; speedup 1.0000x reference)
//
#include <hip/hip_runtime.h>

typedef float  f32x4   __attribute__((ext_vector_type(4)));
typedef float  f32x16  __attribute__((ext_vector_type(16)));
typedef int    i32x4   __attribute__((ext_vector_type(4)));
typedef short  bf16x8  __attribute__((ext_vector_type(8)));
typedef short  s16x4   __attribute__((ext_vector_type(4)));

#define NB   2
#define SEQ  2048
#define EMB  1024
#define NH   16
#define DH   64
#define MATN (NB * SEQ * EMB)   // 4194304 elems per matrix

__device__ inline short f2bf(float f) {
    unsigned u = __float_as_uint(f);
    u += 0x7fffu + ((u >> 16) & 1u);
    return (short)(u >> 16);
}

__device__ inline unsigned cvtpk(float lo, float hi) {
    unsigned r;
    asm("v_cvt_pk_bf16_f32 %0, %1, %2" : "=v"(r) : "v"(lo), "v"(hi));
    return r;
}

__device__ inline float fexp2(float x) {
#if __has_builtin(__builtin_amdgcn_exp2f)
    return __builtin_amdgcn_exp2f(x);
#else
    return exp2f(x);
#endif
}

__device__ inline f32x4 mfma16(bf16x8 a, bf16x8 b, f32x4 c) {
    return __builtin_amdgcn_mfma_f32_16x16x32_bf16(a, b, c, 0, 0, 0);
}
__device__ inline f32x16 mfma32(bf16x8 a, bf16x8 b, f32x16 c) {
    return __builtin_amdgcn_mfma_f32_32x32x16_bf16(a, b, c, 0, 0, 0);
}

// async 16B global -> LDS (wave-uniform LDS base; HW adds lane*16B)
__device__ inline void gload_lds16(const short* g, short* l) {
    __builtin_amdgcn_global_load_lds(
        (const __attribute__((address_space(1))) void*)g,
        (__attribute__((address_space(3))) void*)l, 16, 0, 0);
}

// ---------------------------------------------------------------------------
// Kernel 1: prep. (unchanged)
// ---------------------------------------------------------------------------
__global__ __launch_bounds__(256) void prep_kernel(const float* __restrict__ q,
                                                   const float* __restrict__ k,
                                                   const float* __restrict__ v,
                                                   const float* __restrict__ w0,
                                                   const float* __restrict__ w1,
                                                   const float* __restrict__ w2,
                                                   short* __restrict__ wt,
                                                   short* __restrict__ abf) {
    int blk = blockIdx.x;
    int t = threadIdx.x;
    if (blk < 3072) {
        __shared__ float tile[32][33];
        int mat = blk >> 10;
        int rem = blk & 1023;
        int kt = rem >> 5, nt = rem & 31;
        const float* W = (mat == 0) ? w0 : ((mat == 1) ? w1 : w2);
        int row = t >> 3, c4 = (t & 7) << 2;

        f32x4 val = *(const f32x4*)(W + (kt * 32 + row) * EMB + nt * 32 + c4);
        tile[row][c4 + 0] = val[0];
        tile[row][c4 + 1] = val[1];
        tile[row][c4 + 2] = val[2];
        tile[row][c4 + 3] = val[3];
        __syncthreads();

        int n = nt * 32 + row;
        s16x4 o;
        o[0] = f2bf(tile[c4 + 0][row]);
        o[1] = f2bf(tile[c4 + 1][row]);
        o[2] = f2bf(tile[c4 + 2][row]);
        o[3] = f2bf(tile[c4 + 3][row]);
        *(s16x4*)(wt + mat * (EMB * EMB) + n * EMB + kt * 32 + c4) = o;
    } else {
        long long i = (long long)(blk - 3072) * 2048 + t * 8;
        int mat = (int)(i >> 22);
        int off = (int)(i & (MATN - 1));
        const float* A = (mat == 0) ? q : ((mat == 1) ? k : v);
        f32x4 x = *(const f32x4*)(A + off);
        f32x4 y = *(const f32x4*)(A + off + 4);
        bf16x8 pk;
        pk[0] = f2bf(x[0]); pk[1] = f2bf(x[1]); pk[2] = f2bf(x[2]); pk[3] = f2bf(x[3]);
        pk[4] = f2bf(y[0]); pk[5] = f2bf(y[1]); pk[6] = f2bf(y[2]); pk[7] = f2bf(y[3]);
        *(bf16x8*)(abf + i) = pk;
    }
}

// ---------------------------------------------------------------------------
// Kernel 2: projection GEMM (r8/r14 structure, unchanged).
// ---------------------------------------------------------------------------
template <bool BF16A>
__global__ __launch_bounds__(256) void proj_kernel(const short* __restrict__ abf,
                                                   const float* __restrict__ a0,
                                                   const float* __restrict__ a1,
                                                   const float* __restrict__ a2,
                                                   const float* __restrict__ b0,
                                                   const float* __restrict__ b1,
                                                   const float* __restrict__ b2,
                                                   const short* __restrict__ wt,
                                                   short* __restrict__ qkv) {
    __shared__ __align__(16) short smem[18432];

    int orig = blockIdx.x;                    // 768 blocks, 768%8==0
    int blk = (orig & 7) * 96 + (orig >> 3);  // XCD-contiguous chunks
    int mat = blk >> 8;
    int rem = blk & 255;
    int mt = rem >> 3, nt = rem & 7;

    const float* bias = (mat == 0) ? b0 : ((mat == 1) ? b1 : b2);
    const float* Af = (mat == 0) ? a0 : ((mat == 1) ? a1 : a2);
    const short* Ab = abf + mat * MATN;
    const short* WT = wt + mat * (EMB * EMB);
    short* O = qkv + mat * MATN;
    float scale = (mat == 0) ? 0.125f * 1.44269504f : 1.0f;

    int t = threadIdx.x;
    int lane = t & 63, w = t >> 6;
    int wr = w >> 1, wc = w & 1;
    int lg = lane >> 4, lm = lane & 15;

    int m0 = mt * 128, n0 = nt * 128;

    f32x4 acc[4][4] = {};

    if constexpr (BF16A) {
        const short* gA[4];
        const short* gW[4];
        int ldso[4];
#pragma unroll
        for (int i = 0; i < 4; i++) {
            int u = w * 256 + i * 64 + lane;
            int row = u >> 3;
            int c = (u & 7) ^ (row & 7);
            gA[i] = Ab + (m0 + row) * EMB + c * 8;
            gW[i] = WT + (n0 + row) * EMB + c * 8;
            ldso[i] = (w * 256 + i * 64) * 8;
        }
        int xr = lm & 7;
        for (int k0 = 0; k0 < EMB; k0 += 64) {
#pragma unroll
            for (int i = 0; i < 4; i++) {
                gload_lds16(gA[i] + k0, smem + ldso[i]);
                gload_lds16(gW[i] + k0, smem + 8192 + ldso[i]);
            }
            __syncthreads();
#pragma unroll
            for (int ks = 0; ks < 2; ks++) {
                bf16x8 af[4], bfr[4];
                int cc = (ks * 4 + lg) ^ xr;
#pragma unroll
                for (int mi = 0; mi < 4; mi++)
                    af[mi] = *(const bf16x8*)(smem + (wr * 64 + mi * 16 + lm) * 64 + cc * 8);
#pragma unroll
                for (int ni = 0; ni < 4; ni++)
                    bfr[ni] = *(const bf16x8*)(smem + 8192 + (wc * 64 + ni * 16 + lm) * 64 + cc * 8);
#pragma unroll
                for (int mi = 0; mi < 4; mi++)
#pragma unroll
                    for (int ni = 0; ni < 4; ni++)
                        acc[mi][ni] = mfma16(af[mi], bfr[ni], acc[mi][ni]);
            }
            __syncthreads();
        }
    } else {
        int srow = t >> 1, koff = (t & 1) * 32;
        for (int k0 = 0; k0 < EMB; k0 += 64) {
            const float* ap = Af + (m0 + srow) * EMB + k0 + koff;
#pragma unroll
            for (int i = 0; i < 4; i++) {
                f32x4 x = *(const f32x4*)(ap + i * 8);
                f32x4 y = *(const f32x4*)(ap + i * 8 + 4);
                bf16x8 pk;
                pk[0] = f2bf(x[0]); pk[1] = f2bf(x[1]); pk[2] = f2bf(x[2]); pk[3] = f2bf(x[3]);
                pk[4] = f2bf(y[0]); pk[5] = f2bf(y[1]); pk[6] = f2bf(y[2]); pk[7] = f2bf(y[3]);
                *(bf16x8*)&smem[srow * 72 + koff + i * 8] = pk;
            }
            const short* wp = WT + (n0 + srow) * EMB + k0 + koff;
#pragma unroll
            for (int i = 0; i < 4; i++)
                *(i32x4*)&smem[9216 + srow * 72 + koff + i * 8] = *(const i32x4*)(wp + i * 8);
            __syncthreads();
#pragma unroll
            for (int ks = 0; ks < 2; ks++) {
                bf16x8 af[4], bfr[4];
#pragma unroll
                for (int mi = 0; mi < 4; mi++)
                    af[mi] = *(const bf16x8*)&smem[(wr * 64 + mi * 16 + lm) * 72 + ks * 32 + lg * 8];
#pragma unroll
                for (int ni = 0; ni < 4; ni++)
                    bfr[ni] = *(const bf16x8*)&smem[9216 + (wc * 64 + ni * 16 + lm) * 72 + ks * 32 + lg * 8];
#pragma unroll
                for (int mi = 0; mi < 4; mi++)
#pragma unroll
                    for (int ni = 0; ni < 4; ni++)
                        acc[mi][ni] = mfma16(af[mi], bfr[ni], acc[mi][ni]);
            }
            __syncthreads();
        }
    }

    int bidx = m0 >> 11;
    if (mat == 2) {
#pragma unroll
        for (int ni = 0; ni < 4; ni++) {
            int e = n0 + wc * 64 + ni * 16 + lm;
            float bv = bias[e];
            int h = e >> 6, d = e & 63;
#pragma unroll
            for (int mi = 0; mi < 4; mi++) {
                int s = (m0 + wr * 64 + mi * 16 + lg * 4) & (SEQ - 1);
                s16x4 o;
#pragma unroll
                for (int r = 0; r < 4; r++) o[r] = f2bf(acc[mi][ni][r] + bv);
                *(s16x4*)(O + (((bidx * NH + h) * DH + d) * SEQ) + s) = o;
            }
        }
    } else {
#pragma unroll
        for (int ni = 0; ni < 4; ni++) {
            int e = n0 + wc * 64 + ni * 16 + lm;
            float bv = bias[e];
#pragma unroll
            for (int mi = 0; mi < 4; mi++) {
                int rr = wr * 64 + mi * 16 + lg * 4;
#pragma unroll
                for (int r = 0; r < 4; r++)
                    smem[(rr + r) * 136 + wc * 64 + ni * 16 + lm] =
                        f2bf((acc[mi][ni][r] + bv) * scale);
            }
        }
        __syncthreads();
        int r = t >> 1, half = t & 1;
        int h = (n0 + half * 64) >> 6;
        int s = (m0 + r) & (SEQ - 1);
        short* dst = O + (((long long)bidx * NH + h) * SEQ + s) * DH;
        const short* srcp = smem + r * 136 + half * 64;
#pragma unroll
        for (int j = 0; j < 8; j++)
            *(i32x4*)(dst + j * 8) = *(const i32x4*)(srcp + j * 8);
    }
}

// ---------------------------------------------------------------------------
// Kernel 3: fused attention (r14 arithmetic). r21: pass-2 K fragments come
// DIRECTLY from global (coalesced 1KB/instruction-pair; K is L2/L3-resident —
// r6's corrected FETCH=12.3MB proves no HBM over-fetch; r6's regression is
// attributed to its scalar V gather, absent here). Removes all pass-2 K LDS
// writes+reads (the 4x-redundant serial-chain term). Pass 1 keeps r19's
// de-padded swizzled kbuf. LDS 32KB -> 5 blocks/CU. Cached attn stores.
// ---------------------------------------------------------------------------
__global__ __launch_bounds__(256) void attn_kernel(const short* __restrict__ qkv,
                                                   float* __restrict__ out,
                                                   float* __restrict__ attn) {
    const short* Qb = qkv;
    const short* Kb = qkv + MATN;
    const short* Vt = qkv + 2 * MATN;   // [bh][64][2048]

    __shared__ __align__(16) short kbuf[2][4096];   // pass-1 K tile, swizzled
    __shared__ __align__(16) short vbuf[2][4096];   // V panels; aliases lds_rs
    float* lds_rs = (float*)&vbuf[0][0];            // 4x32 floats, pass-1 only

    int orig = blockIdx.x;                 // 1024 blocks, 1024%8==0
    int wg = (orig & 7) * 128 + (orig >> 3);
    int bh = wg >> 5;
    int q0 = (wg & 31) * 64;
    int b = bh >> 4, hq = bh & 15;

    int t = threadIdx.x, lane = t & 63, w = t >> 6;
    int lg = lane >> 4, lm = lane & 15;
    int srow = t >> 2, sch = t & 3;

    const short* kbase = Kb + (long long)bh * SEQ * DH;
    const short* vbase = Vt + (long long)bh * DH * SEQ;

    // K staging swizzle (pass 1, r19 pattern): chunk ^= row&7, write & read
    int kc0 = ((sch * 2)     ^ (srow & 7)) * 8;
    int kc1 = ((sch * 2 + 1) ^ (srow & 7)) * 8;

    // Q fragments for pass 2 (16x16 B-op) — direct from global
    bf16x8 qf0, qf1;
    {
        const short* qrow = Qb + ((long long)bh * SEQ + q0 + w * 16 + lm) * DH + lg * 8;
        qf0 = *(const bf16x8*)(qrow);
        qf1 = *(const bf16x8*)(qrow + 32);
    }

    // Q fragments for pass 1 (32x32 B-op): wave covers q-half (w&1)
    int l31 = lane & 31, l5 = lane >> 5;
    int khalf = w >> 1;
    bf16x8 qw[4];
    {
        const short* qr = Qb + ((long long)bh * SEQ + q0 + (w & 1) * 32 + l31) * DH + l5 * 8;
        qw[0] = *(const bf16x8*)(qr);
        qw[1] = *(const bf16x8*)(qr + 16);
        qw[2] = *(const bf16x8*)(qr + 32);
        qw[3] = *(const bf16x8*)(qr + 48);
    }
    // pass-1 read offsets (fixed per thread): logical chunks l5+2j, row swz
    int xr1 = l31 & 7;
    int p1o0 = ((l5    ) ^ xr1) * 8;
    int p1o1 = ((l5 + 2) ^ xr1) * 8;
    int p1o2 = ((l5 + 4) ^ xr1) * 8;
    int p1o3 = ((l5 + 6) ^ xr1) * 8;
    int p1row = (khalf * 32 + l31) * 64;

    // ---- pass 1: softmax denominators (dbuf K, 1 barrier/tile; 32x32 MFMA) ----
    i32x4 kr0, kr1;
    {
        const short* kp = kbase + srow * DH + sch * 16;
        kr0 = *(const i32x4*)(kp); kr1 = *(const i32x4*)(kp + 8);
    }
    float rsum = 0.0f;
    for (int kt = 0; kt < 32; kt++) {
        *(i32x4*)&kbuf[kt & 1][srow * 64 + kc0] = kr0;
        *(i32x4*)&kbuf[kt & 1][srow * 64 + kc1] = kr1;
        __syncthreads();
        if (kt < 31) {
            const short* kp = kbase + ((kt + 1) * 64 + srow) * DH + sch * 16;
            kr0 = *(const i32x4*)(kp); kr1 = *(const i32x4*)(kp + 8);
        }
        const short* kb = &kbuf[kt & 1][p1row];
        f32x16 s = {};
        __builtin_amdgcn_s_setprio(1);
        s = mfma32(*(const bf16x8*)(kb + p1o0), qw[0], s);
        s = mfma32(*(const bf16x8*)(kb + p1o1), qw[1], s);
        s = mfma32(*(const bf16x8*)(kb + p1o2), qw[2], s);
        s = mfma32(*(const bf16x8*)(kb + p1o3), qw[3], s);
        __builtin_amdgcn_s_setprio(0);
#pragma unroll
        for (int r = 0; r < 16; r++) rsum += fexp2(s[r]);
    }
    rsum += __shfl_xor(rsum, 32);            // combine key-row halves (same q)
    if (lane < 32) lds_rs[w * 32 + lane] = rsum;   // q=(w&1)*32+lane partials
    __syncthreads();
    float ml2r;
    {
        int q = w * 16 + lm;                 // pass-2 q-row of this thread
        float tot = (q < 32) ? (lds_rs[q] + lds_rs[2 * 32 + q])
                             : (lds_rs[32 + q - 32] + lds_rs[3 * 32 + q - 32]);
        ml2r = -__log2f(tot);                // fold normalization into C-init
    }
    __syncthreads();                         // lds_rs read done before vbuf write

    // ---- pass 2: attn write + PV (dbuf V, 1 barrier/tile; K direct-global) ----
    f32x4 oacc[4] = {};
    float* arow = attn + ((long long)bh * SEQ + q0 + w * 16 + lm) * SEQ;

    // V packed-panel addr: elem(key=32ks+16jh+4g+jl, d=16di+dl)
    //   -> di*1024 + ks*512 + g*128 + dl*8 + jh*4 + jl
    int vA0 = (srow >> 4) * 1024 + (sch >> 1) * 512 + (srow & 15) * 8 + (sch & 1) * 4;

    // per-thread K fragment base (row = ki*16+lm, chunks lg*8 / +32)
    const short* kgf = kbase + (long long)lm * DH + lg * 8;

    i32x4 vr0, vr1;
    {
        const short* vp = vbase + srow * SEQ + sch * 16;
        vr0 = *(const i32x4*)(vp); vr1 = *(const i32x4*)(vp + 8);
    }

    for (int kt = 0; kt < 32; kt++) {
        union { i32x4 v; s16x4 h[2]; } u0, u1;
        u0.v = vr0; u1.v = vr1;
        *(s16x4*)&vbuf[kt & 1][vA0]       = u0.h[0];
        *(s16x4*)&vbuf[kt & 1][vA0 + 128] = u0.h[1];
        *(s16x4*)&vbuf[kt & 1][vA0 + 256] = u1.h[0];
        *(s16x4*)&vbuf[kt & 1][vA0 + 384] = u1.h[1];
        __syncthreads();
        if (kt < 31) {
            const short* vp = vbase + srow * SEQ + (kt + 1) * 64 + sch * 16;
            vr0 = *(const i32x4*)(vp); vr1 = *(const i32x4*)(vp + 8);
        }

        // K fragments direct from global (L2-hot; 8 independent loads)
        const short* kg = kgf + (long long)kt * 64 * DH;
        bf16x8 kf0[4], kf1[4];
#pragma unroll
        for (int ki = 0; ki < 4; ki++) {
            kf0[ki] = *(const bf16x8*)(kg + ki * 16 * DH);
            kf1[ki] = *(const bf16x8*)(kg + ki * 16 * DH + 32);
        }

        float p[4][4];
#pragma unroll
        for (int ki = 0; ki < 4; ki++) {
            f32x4 s = {ml2r, ml2r, ml2r, ml2r};
            __builtin_amdgcn_s_setprio(1);
            s = mfma16(kf0[ki], qf0, s);
            s = mfma16(kf1[ki], qf1, s);
            __builtin_amdgcn_s_setprio(0);
#pragma unroll
            for (int r = 0; r < 4; r++) p[ki][r] = fexp2(s[r]);
            f32x4 st = {p[ki][0], p[ki][1], p[ki][2], p[ki][3]};
            *(f32x4*)(arow + kt * 64 + ki * 16 + lg * 4) = st;   // cached store
        }

        // P^T -> bf16 B-fragments via v_cvt_pk_bf16_f32
        bf16x8 pb[2];
#pragma unroll
        for (int ks = 0; ks < 2; ks++) {
            union { unsigned d[4]; bf16x8 v; } up;
            up.d[0] = cvtpk(p[2 * ks + 0][0], p[2 * ks + 0][1]);
            up.d[1] = cvtpk(p[2 * ks + 0][2], p[2 * ks + 0][3]);
            up.d[2] = cvtpk(p[2 * ks + 1][0], p[2 * ks + 1][1]);
            up.d[3] = cvtpk(p[2 * ks + 1][2], p[2 * ks + 1][3]);
            pb[ks] = up.v;
        }

        // PV: O^T += V^T · P^T ; fragment = contiguous b128 read
        __builtin_amdgcn_s_setprio(1);
#pragma unroll
        for (int di = 0; di < 4; di++) {
#pragma unroll
            for (int ks = 0; ks < 2; ks++) {
                bf16x8 vf = *(const bf16x8*)&vbuf[kt & 1][(di * 2 + ks) * 512 + (lg * 16 + lm) * 8];
                oacc[di] = mfma16(vf, pb[ks], oacc[di]);
            }
        }
        __builtin_amdgcn_s_setprio(0);
    }

    // write out[b][s][h*64+d] from O^T fragments (rows d, cols q)
    float* op = out + ((long long)b * SEQ + q0 + w * 16 + lm) * EMB + hq * DH;
#pragma unroll
    for (int di = 0; di < 4; di++) {
        __builtin_nontemporal_store(oacc[di], (f32x4*)(op + di * 16 + lg * 4));
    }
}

// ---------------------------------------------------------------------------
extern "C" void kernel_launch(void* const* d_in, const int* in_sizes, int n_in,
                              void* d_out, int out_size, void* d_ws, size_t ws_size,
                              hipStream_t stream) {
    const float* query = (const float*)d_in[0];
    const float* key   = (const float*)d_in[1];
    const float* value = (const float*)d_in[2];
    const float* wq    = (const float*)d_in[3];
    const float* bq    = (const float*)d_in[4];
    const float* wk    = (const float*)d_in[5];
    const float* bk    = (const float*)d_in[6];
    const float* wv    = (const float*)d_in[7];
    const float* bv    = (const float*)d_in[8];

    float* out  = (float*)d_out;
    float* attn = out + (long long)NB * SEQ * EMB;

    // workspace: wt (6MB) [+ abf (25.2MB) if it fits] + qkv (25.2MB)
    size_t need_full = ((size_t)3 * EMB * EMB + 6ull * MATN) * sizeof(short);
    bool bf16a = ws_size >= need_full;

    short* wt  = (short*)d_ws;
    short* abf = wt + 3 * (EMB * EMB);
    short* qkv = bf16a ? (abf + 3 * MATN) : abf;

    hipLaunchKernelGGL(prep_kernel, dim3(bf16a ? 9216 : 3072), dim3(256), 0, stream,
                       query, key, value, wq, wk, wv, wt, abf);
    if (bf16a) {
        hipLaunchKernelGGL((proj_kernel<true>), dim3(768), dim3(256), 0, stream,
                           abf, query, key, value, bq, bk, bv, wt, qkv);
    } else {
        hipLaunchKernelGGL((proj_kernel<false>), dim3(768), dim3(256), 0, stream,
                           abf, query, key, value, bq, bk, bv, wt, qkv);
    }
    hipLaunchKernelGGL(attn_kernel, dim3(1024), dim3(256), 0, stream,
                       qkv, out, attn);
}

// Round 22
// 242.148 us; speedup vs baseline: 1.2112x; 1.2112x over previous
//
#include <hip/hip_runtime.h>

typedef float  f32x4   __attribute__((ext_vector_type(4)));
typedef float  f32x16  __attribute__((ext_vector_type(16)));
typedef int    i32x4   __attribute__((ext_vector_type(4)));
typedef short  bf16x8  __attribute__((ext_vector_type(8)));
typedef short  s16x4   __attribute__((ext_vector_type(4)));

#define NB   2
#define SEQ  2048
#define EMB  1024
#define NH   16
#define DH   64
#define MATN (NB * SEQ * EMB)   // 4194304 elems per matrix

__device__ inline short f2bf(float f) {
    unsigned u = __float_as_uint(f);
    u += 0x7fffu + ((u >> 16) & 1u);
    return (short)(u >> 16);
}

__device__ inline unsigned cvtpk(float lo, float hi) {
    unsigned r;
    asm("v_cvt_pk_bf16_f32 %0, %1, %2" : "=v"(r) : "v"(lo), "v"(hi));
    return r;
}

__device__ inline float fexp2(float x) {
#if __has_builtin(__builtin_amdgcn_exp2f)
    return __builtin_amdgcn_exp2f(x);
#else
    return exp2f(x);
#endif
}

__device__ inline f32x4 mfma16(bf16x8 a, bf16x8 b, f32x4 c) {
    return __builtin_amdgcn_mfma_f32_16x16x32_bf16(a, b, c, 0, 0, 0);
}
__device__ inline f32x16 mfma32(bf16x8 a, bf16x8 b, f32x16 c) {
    return __builtin_amdgcn_mfma_f32_32x32x16_bf16(a, b, c, 0, 0, 0);
}

// async 16B global -> LDS (wave-uniform LDS base; HW adds lane*16B)
__device__ inline void gload_lds16(const short* g, short* l) {
    __builtin_amdgcn_global_load_lds(
        (const __attribute__((address_space(1))) void*)g,
        (__attribute__((address_space(3))) void*)l, 16, 0, 0);
}

// ---------------------------------------------------------------------------
// Kernel 1: prep.
//   blocks [0,3072):    W [k][n] fp32 -> W^T [n][k] bf16 (transpose+convert)
//   blocks [3072,9216): activations fp32 -> bf16 (only in BF16A mode)
// ---------------------------------------------------------------------------
__global__ __launch_bounds__(256) void prep_kernel(const float* __restrict__ q,
                                                   const float* __restrict__ k,
                                                   const float* __restrict__ v,
                                                   const float* __restrict__ w0,
                                                   const float* __restrict__ w1,
                                                   const float* __restrict__ w2,
                                                   short* __restrict__ wt,
                                                   short* __restrict__ abf) {
    int blk = blockIdx.x;
    int t = threadIdx.x;
    if (blk < 3072) {
        __shared__ float tile[32][33];
        int mat = blk >> 10;
        int rem = blk & 1023;
        int kt = rem >> 5, nt = rem & 31;
        const float* W = (mat == 0) ? w0 : ((mat == 1) ? w1 : w2);
        int row = t >> 3, c4 = (t & 7) << 2;

        f32x4 val = *(const f32x4*)(W + (kt * 32 + row) * EMB + nt * 32 + c4);
        tile[row][c4 + 0] = val[0];
        tile[row][c4 + 1] = val[1];
        tile[row][c4 + 2] = val[2];
        tile[row][c4 + 3] = val[3];
        __syncthreads();

        int n = nt * 32 + row;
        s16x4 o;
        o[0] = f2bf(tile[c4 + 0][row]);
        o[1] = f2bf(tile[c4 + 1][row]);
        o[2] = f2bf(tile[c4 + 2][row]);
        o[3] = f2bf(tile[c4 + 3][row]);
        *(s16x4*)(wt + mat * (EMB * EMB) + n * EMB + kt * 32 + c4) = o;
    } else {
        long long i = (long long)(blk - 3072) * 2048 + t * 8;
        int mat = (int)(i >> 22);
        int off = (int)(i & (MATN - 1));
        const float* A = (mat == 0) ? q : ((mat == 1) ? k : v);
        f32x4 x = *(const f32x4*)(A + off);
        f32x4 y = *(const f32x4*)(A + off + 4);
        bf16x8 pk;
        pk[0] = f2bf(x[0]); pk[1] = f2bf(x[1]); pk[2] = f2bf(x[2]); pk[3] = f2bf(x[3]);
        pk[4] = f2bf(y[0]); pk[5] = f2bf(y[1]); pk[6] = f2bf(y[2]); pk[7] = f2bf(y[3]);
        *(bf16x8*)(abf + i) = pk;
    }
}

// ---------------------------------------------------------------------------
// Kernel 2: projection GEMM (r8 structure). BF16A: global_load_lds staging
// with both-sides XOR chunk swizzle. fp32 fallback: padded reg-staging.
// Q,K stored [B,H,S,Dh]; Q pre-scaled by 0.125*log2(e). V stored [B,H,Dh,S].
// ---------------------------------------------------------------------------
template <bool BF16A>
__global__ __launch_bounds__(256) void proj_kernel(const short* __restrict__ abf,
                                                   const float* __restrict__ a0,
                                                   const float* __restrict__ a1,
                                                   const float* __restrict__ a2,
                                                   const float* __restrict__ b0,
                                                   const float* __restrict__ b1,
                                                   const float* __restrict__ b2,
                                                   const short* __restrict__ wt,
                                                   short* __restrict__ qkv) {
    __shared__ __align__(16) short smem[18432];

    int orig = blockIdx.x;                    // 768 blocks, 768%8==0
    int blk = (orig & 7) * 96 + (orig >> 3);  // XCD-contiguous chunks
    int mat = blk >> 8;
    int rem = blk & 255;
    int mt = rem >> 3, nt = rem & 7;

    const float* bias = (mat == 0) ? b0 : ((mat == 1) ? b1 : b2);
    const float* Af = (mat == 0) ? a0 : ((mat == 1) ? a1 : a2);
    const short* Ab = abf + mat * MATN;
    const short* WT = wt + mat * (EMB * EMB);
    short* O = qkv + mat * MATN;
    float scale = (mat == 0) ? 0.125f * 1.44269504f : 1.0f;

    int t = threadIdx.x;
    int lane = t & 63, w = t >> 6;
    int wr = w >> 1, wc = w & 1;
    int lg = lane >> 4, lm = lane & 15;

    int m0 = mt * 128, n0 = nt * 128;

    f32x4 acc[4][4] = {};

    if constexpr (BF16A) {
        const short* gA[4];
        const short* gW[4];
        int ldso[4];
#pragma unroll
        for (int i = 0; i < 4; i++) {
            int u = w * 256 + i * 64 + lane;
            int row = u >> 3;
            int c = (u & 7) ^ (row & 7);
            gA[i] = Ab + (m0 + row) * EMB + c * 8;
            gW[i] = WT + (n0 + row) * EMB + c * 8;
            ldso[i] = (w * 256 + i * 64) * 8;
        }
        int xr = lm & 7;
        for (int k0 = 0; k0 < EMB; k0 += 64) {
#pragma unroll
            for (int i = 0; i < 4; i++) {
                gload_lds16(gA[i] + k0, smem + ldso[i]);
                gload_lds16(gW[i] + k0, smem + 8192 + ldso[i]);
            }
            __syncthreads();
#pragma unroll
            for (int ks = 0; ks < 2; ks++) {
                bf16x8 af[4], bfr[4];
                int cc = (ks * 4 + lg) ^ xr;
#pragma unroll
                for (int mi = 0; mi < 4; mi++)
                    af[mi] = *(const bf16x8*)(smem + (wr * 64 + mi * 16 + lm) * 64 + cc * 8);
#pragma unroll
                for (int ni = 0; ni < 4; ni++)
                    bfr[ni] = *(const bf16x8*)(smem + 8192 + (wc * 64 + ni * 16 + lm) * 64 + cc * 8);
#pragma unroll
                for (int mi = 0; mi < 4; mi++)
#pragma unroll
                    for (int ni = 0; ni < 4; ni++)
                        acc[mi][ni] = mfma16(af[mi], bfr[ni], acc[mi][ni]);
            }
            __syncthreads();
        }
    } else {
        int srow = t >> 1, koff = (t & 1) * 32;
        for (int k0 = 0; k0 < EMB; k0 += 64) {
            const float* ap = Af + (m0 + srow) * EMB + k0 + koff;
#pragma unroll
            for (int i = 0; i < 4; i++) {
                f32x4 x = *(const f32x4*)(ap + i * 8);
                f32x4 y = *(const f32x4*)(ap + i * 8 + 4);
                bf16x8 pk;
                pk[0] = f2bf(x[0]); pk[1] = f2bf(x[1]); pk[2] = f2bf(x[2]); pk[3] = f2bf(x[3]);
                pk[4] = f2bf(y[0]); pk[5] = f2bf(y[1]); pk[6] = f2bf(y[2]); pk[7] = f2bf(y[3]);
                *(bf16x8*)&smem[srow * 72 + koff + i * 8] = pk;
            }
            const short* wp = WT + (n0 + srow) * EMB + k0 + koff;
#pragma unroll
            for (int i = 0; i < 4; i++)
                *(i32x4*)&smem[9216 + srow * 72 + koff + i * 8] = *(const i32x4*)(wp + i * 8);
            __syncthreads();
#pragma unroll
            for (int ks = 0; ks < 2; ks++) {
                bf16x8 af[4], bfr[4];
#pragma unroll
                for (int mi = 0; mi < 4; mi++)
                    af[mi] = *(const bf16x8*)&smem[(wr * 64 + mi * 16 + lm) * 72 + ks * 32 + lg * 8];
#pragma unroll
                for (int ni = 0; ni < 4; ni++)
                    bfr[ni] = *(const bf16x8*)&smem[9216 + (wc * 64 + ni * 16 + lm) * 72 + ks * 32 + lg * 8];
#pragma unroll
                for (int mi = 0; mi < 4; mi++)
#pragma unroll
                    for (int ni = 0; ni < 4; ni++)
                        acc[mi][ni] = mfma16(af[mi], bfr[ni], acc[mi][ni]);
            }
            __syncthreads();
        }
    }

    int bidx = m0 >> 11;
    if (mat == 2) {
#pragma unroll
        for (int ni = 0; ni < 4; ni++) {
            int e = n0 + wc * 64 + ni * 16 + lm;
            float bv = bias[e];
            int h = e >> 6, d = e & 63;
#pragma unroll
            for (int mi = 0; mi < 4; mi++) {
                int s = (m0 + wr * 64 + mi * 16 + lg * 4) & (SEQ - 1);
                s16x4 o;
#pragma unroll
                for (int r = 0; r < 4; r++) o[r] = f2bf(acc[mi][ni][r] + bv);
                *(s16x4*)(O + (((bidx * NH + h) * DH + d) * SEQ) + s) = o;
            }
        }
    } else {
#pragma unroll
        for (int ni = 0; ni < 4; ni++) {
            int e = n0 + wc * 64 + ni * 16 + lm;
            float bv = bias[e];
#pragma unroll
            for (int mi = 0; mi < 4; mi++) {
                int rr = wr * 64 + mi * 16 + lg * 4;
#pragma unroll
                for (int r = 0; r < 4; r++)
                    smem[(rr + r) * 136 + wc * 64 + ni * 16 + lm] =
                        f2bf((acc[mi][ni][r] + bv) * scale);
            }
        }
        __syncthreads();
        int r = t >> 1, half = t & 1;
        int h = (n0 + half * 64) >> 6;
        int s = (m0 + r) & (SEQ - 1);
        short* dst = O + (((long long)bidx * NH + h) * SEQ + s) * DH;
        const short* srcp = smem + r * 136 + half * 64;
#pragma unroll
        for (int j = 0; j < 8; j++)
            *(i32x4*)(dst + j * 8) = *(const i32x4*)(srcp + j * 8);
    }
}

// ---------------------------------------------------------------------------
// Kernel 3: fused attention — r14-exact (session best, 243.9us).
// Pass 1: 32x32 MFMA, dbuf padded kbuf. Pass 2: 16x16 MFMA, normalization
// folded into MFMA C-init; CACHED attn stores (the -32us mechanism win);
// nt out stores; __syncthreads barriers; setprio around MFMA clusters.
// ---------------------------------------------------------------------------
__global__ __launch_bounds__(256) void attn_kernel(const short* __restrict__ qkv,
                                                   float* __restrict__ out,
                                                   float* __restrict__ attn) {
    const short* Qb = qkv;
    const short* Kb = qkv + MATN;
    const short* Vt = qkv + 2 * MATN;   // [bh][64][2048]

    __shared__ __align__(16) short kbuf[2][64][72];
    __shared__ __align__(16) short vbuf[2][4096];
    __shared__ float lds_rs[4][32];

    int orig = blockIdx.x;                 // 1024 blocks, 1024%8==0
    int wg = (orig & 7) * 128 + (orig >> 3);
    int bh = wg >> 5;
    int q0 = (wg & 31) * 64;
    int b = bh >> 4, hq = bh & 15;

    int t = threadIdx.x, lane = t & 63, w = t >> 6;
    int lg = lane >> 4, lm = lane & 15;
    int srow = t >> 2, sch = t & 3;

    const short* kbase = Kb + (long long)bh * SEQ * DH;
    const short* vbase = Vt + (long long)bh * DH * SEQ;

    // Q fragments for pass 2 (16x16 B-op) — direct from global
    bf16x8 qf0, qf1;
    {
        const short* qrow = Qb + ((long long)bh * SEQ + q0 + w * 16 + lm) * DH + lg * 8;
        qf0 = *(const bf16x8*)(qrow);
        qf1 = *(const bf16x8*)(qrow + 32);
    }

    // Q fragments for pass 1 (32x32 B-op): wave covers q-half (w&1)
    int l31 = lane & 31, l5 = lane >> 5;
    int khalf = w >> 1;
    bf16x8 qw[4];
    {
        const short* qr = Qb + ((long long)bh * SEQ + q0 + (w & 1) * 32 + l31) * DH + l5 * 8;
        qw[0] = *(const bf16x8*)(qr);
        qw[1] = *(const bf16x8*)(qr + 16);
        qw[2] = *(const bf16x8*)(qr + 32);
        qw[3] = *(const bf16x8*)(qr + 48);
    }

    // ---- pass 1: softmax denominators (dbuf K, 1 barrier/tile; 32x32 MFMA) ----
    i32x4 kr0, kr1;
    {
        const short* kp = kbase + srow * DH + sch * 16;
        kr0 = *(const i32x4*)(kp); kr1 = *(const i32x4*)(kp + 8);
    }
    float rsum = 0.0f;
    for (int kt = 0; kt < 32; kt++) {
        *(i32x4*)&kbuf[kt & 1][srow][sch * 16]     = kr0;
        *(i32x4*)&kbuf[kt & 1][srow][sch * 16 + 8] = kr1;
        __syncthreads();
        if (kt < 31) {
            const short* kp = kbase + ((kt + 1) * 64 + srow) * DH + sch * 16;
            kr0 = *(const i32x4*)(kp); kr1 = *(const i32x4*)(kp + 8);
        }
        const short* kb = &kbuf[kt & 1][khalf * 32 + l31][l5 * 8];
        f32x16 s = {};
        __builtin_amdgcn_s_setprio(1);
        s = mfma32(*(const bf16x8*)(kb),      qw[0], s);
        s = mfma32(*(const bf16x8*)(kb + 16), qw[1], s);
        s = mfma32(*(const bf16x8*)(kb + 32), qw[2], s);
        s = mfma32(*(const bf16x8*)(kb + 48), qw[3], s);
        __builtin_amdgcn_s_setprio(0);
#pragma unroll
        for (int r = 0; r < 16; r++) rsum += fexp2(s[r]);
    }
    rsum += __shfl_xor(rsum, 32);            // combine key-row halves (same q)
    if (lane < 32) lds_rs[w][lane] = rsum;   // per-wave partial for q=(w&1)*32+lane
    __syncthreads();
    float ml2r;
    {
        int q = w * 16 + lm;                 // pass-2 q-row of this thread
        float tot = (q < 32) ? (lds_rs[0][q] + lds_rs[2][q])
                             : (lds_rs[1][q - 32] + lds_rs[3][q - 32]);
        ml2r = -__log2f(tot);                // fold normalization into C-init
    }

    // ---- pass 2: attn write + PV (dbuf K+V, 1 barrier/tile; 16x16 MFMA) ----
    f32x4 oacc[4] = {};
    float* arow = attn + ((long long)bh * SEQ + q0 + w * 16 + lm) * SEQ;

    // V packed-panel addr: elem(key=32ks+16jh+4g+jl, d=16di+dl)
    //   -> di*1024 + ks*512 + g*128 + dl*8 + jh*4 + jl
    int vA0 = (srow >> 4) * 1024 + (sch >> 1) * 512 + (srow & 15) * 8 + (sch & 1) * 4;

    i32x4 vr0, vr1;
    {
        const short* kp = kbase + srow * DH + sch * 16;
        kr0 = *(const i32x4*)(kp); kr1 = *(const i32x4*)(kp + 8);
        const short* vp = vbase + srow * SEQ + sch * 16;
        vr0 = *(const i32x4*)(vp); vr1 = *(const i32x4*)(vp + 8);
    }

    for (int kt = 0; kt < 32; kt++) {
        *(i32x4*)&kbuf[kt & 1][srow][sch * 16]     = kr0;
        *(i32x4*)&kbuf[kt & 1][srow][sch * 16 + 8] = kr1;
        union { i32x4 v; s16x4 h[2]; } u0, u1;
        u0.v = vr0; u1.v = vr1;
        *(s16x4*)&vbuf[kt & 1][vA0]       = u0.h[0];
        *(s16x4*)&vbuf[kt & 1][vA0 + 128] = u0.h[1];
        *(s16x4*)&vbuf[kt & 1][vA0 + 256] = u1.h[0];
        *(s16x4*)&vbuf[kt & 1][vA0 + 384] = u1.h[1];
        __syncthreads();
        if (kt < 31) {
            const short* kp = kbase + ((kt + 1) * 64 + srow) * DH + sch * 16;
            kr0 = *(const i32x4*)(kp); kr1 = *(const i32x4*)(kp + 8);
            const short* vp = vbase + srow * SEQ + (kt + 1) * 64 + sch * 16;
            vr0 = *(const i32x4*)(vp); vr1 = *(const i32x4*)(vp + 8);
        }

        float p[4][4];
#pragma unroll
        for (int ki = 0; ki < 4; ki++) {
            f32x4 s = {ml2r, ml2r, ml2r, ml2r};
            bf16x8 kf0 = *(const bf16x8*)&kbuf[kt & 1][ki * 16 + lm][lg * 8];
            bf16x8 kf1 = *(const bf16x8*)&kbuf[kt & 1][ki * 16 + lm][32 + lg * 8];
            __builtin_amdgcn_s_setprio(1);
            s = mfma16(kf0, qf0, s);
            s = mfma16(kf1, qf1, s);
            __builtin_amdgcn_s_setprio(0);
#pragma unroll
            for (int r = 0; r < 4; r++) p[ki][r] = fexp2(s[r]);
            f32x4 st = {p[ki][0], p[ki][1], p[ki][2], p[ki][3]};
            *(f32x4*)(arow + kt * 64 + ki * 16 + lg * 4) = st;   // cached store
        }

        // P^T -> bf16 B-fragments via v_cvt_pk_bf16_f32
        bf16x8 pb[2];
#pragma unroll
        for (int ks = 0; ks < 2; ks++) {
            union { unsigned d[4]; bf16x8 v; } up;
            up.d[0] = cvtpk(p[2 * ks + 0][0], p[2 * ks + 0][1]);
            up.d[1] = cvtpk(p[2 * ks + 0][2], p[2 * ks + 0][3]);
            up.d[2] = cvtpk(p[2 * ks + 1][0], p[2 * ks + 1][1]);
            up.d[3] = cvtpk(p[2 * ks + 1][2], p[2 * ks + 1][3]);
            pb[ks] = up.v;
        }

        // PV: O^T += V^T · P^T ; fragment = contiguous b128 read
        __builtin_amdgcn_s_setprio(1);
#pragma unroll
        for (int di = 0; di < 4; di++) {
#pragma unroll
            for (int ks = 0; ks < 2; ks++) {
                bf16x8 vf = *(const bf16x8*)&vbuf[kt & 1][(di * 2 + ks) * 512 + (lg * 16 + lm) * 8];
                oacc[di] = mfma16(vf, pb[ks], oacc[di]);
            }
        }
        __builtin_amdgcn_s_setprio(0);
    }

    // write out[b][s][h*64+d] from O^T fragments (rows d, cols q)
    float* op = out + ((long long)b * SEQ + q0 + w * 16 + lm) * EMB + hq * DH;
#pragma unroll
    for (int di = 0; di < 4; di++) {
        __builtin_nontemporal_store(oacc[di], (f32x4*)(op + di * 16 + lg * 4));
    }
}

// ---------------------------------------------------------------------------
extern "C" void kernel_launch(void* const* d_in, const int* in_sizes, int n_in,
                              void* d_out, int out_size, void* d_ws, size_t ws_size,
                              hipStream_t stream) {
    const float* query = (const float*)d_in[0];
    const float* key   = (const float*)d_in[1];
    const float* value = (const float*)d_in[2];
    const float* wq    = (const float*)d_in[3];
    const float* bq    = (const float*)d_in[4];
    const float* wk    = (const float*)d_in[5];
    const float* bk    = (const float*)d_in[6];
    const float* wv    = (const float*)d_in[7];
    const float* bv    = (const float*)d_in[8];

    float* out  = (float*)d_out;
    float* attn = out + (long long)NB * SEQ * EMB;

    // workspace: wt (6MB) [+ abf (25.2MB) if it fits] + qkv (25.2MB)
    size_t need_full = ((size_t)3 * EMB * EMB + 6ull * MATN) * sizeof(short);
    bool bf16a = ws_size >= need_full;

    short* wt  = (short*)d_ws;
    short* abf = wt + 3 * (EMB * EMB);
    short* qkv = bf16a ? (abf + 3 * MATN) : abf;

    hipLaunchKernelGGL(prep_kernel, dim3(bf16a ? 9216 : 3072), dim3(256), 0, stream,
                       query, key, value, wq, wk, wv, wt, abf);
    if (bf16a) {
        hipLaunchKernelGGL((proj_kernel<true>), dim3(768), dim3(256), 0, stream,
                           abf, query, key, value, bq, bk, bv, wt, qkv);
    } else {
        hipLaunchKernelGGL((proj_kernel<false>), dim3(768), dim3(256), 0, stream,
                           abf, query, key, value, bq, bk, bv, wt, qkv);
    }
    hipLaunchKernelGGL(attn_kernel, dim3(1024), dim3(256), 0, stream,
                       qkv, out, attn);
}